// Round 7
// baseline (454.710 us; speedup 1.0000x reference)
//
#include <hip/hip_runtime.h>
#include <math.h>

#define S_LEN 2048
#define BATCH 2
#define NH 16
#define NKV 4
#define DKQ 128
#define DVV 128
#define HID 2048
#define QKV_DIM 3072
#define M_TOK 4096

typedef _Float16 halfx8 __attribute__((ext_vector_type(8)));
typedef _Float16 halfx4 __attribute__((ext_vector_type(4)));
typedef float floatx4 __attribute__((ext_vector_type(4)));

#define AS1 __attribute__((address_space(1)))
#define AS3 __attribute__((address_space(3)))
#define GLD16(gp, lp) __builtin_amdgcn_global_load_lds((AS1 const void*)(gp), (AS3 void*)(lp), 16, 0, 0)
#define MFMA16(a, b, c) __builtin_amdgcn_mfma_f32_16x16x32_f16(a, b, c, 0, 0, 0)
#define SBAR() asm volatile("s_barrier" ::: "memory")

#define PA_STRIDE 81920  // per (bh,chunk): M 32768 | E 16384 | B 32768 (8 panels of [128][16])

__device__ __forceinline__ float sigmoidf_(float x) { return 1.f / (1.f + __expf(-x)); }

// ---------------- f32 -> f16 convert (8 elems/thread) ----------------
__global__ __launch_bounds__(256) void cvt_f16(const float* __restrict__ in,
                                               _Float16* __restrict__ out, int n8) {
  int i = blockIdx.x * 256 + threadIdx.x;
  if (i >= n8) return;
  const float4* p = (const float4*)in;
  float4 a = p[2 * (size_t)i], b = p[2 * (size_t)i + 1];
  halfx8 o;
  o[0] = (_Float16)a.x; o[1] = (_Float16)a.y; o[2] = (_Float16)a.z; o[3] = (_Float16)a.w;
  o[4] = (_Float16)b.x; o[5] = (_Float16)b.y; o[6] = (_Float16)b.z; o[7] = (_Float16)b.w;
  *(halfx8*)(out + (size_t)i * 8) = o;
}

// ---------------- fp16 MFMA GEMM NT, 128x128 tile, BK=64, 2-phase schedule ----------------
// C[M,N] f32 = A[M,K] * B[N,K]^T.  256 threads = 4 waves (2M x 2N), per-wave C 64x64.
// LDS 64KiB (2 blocks/CU -> independent barrier groups overlap each other's drains):
//   2 K-tile buffers x (A 128x64 + B 128x64) f16.
// Full 3-bit column swizzle (verified conflict-free in R4): LDS[r][c16] = global[r][c16^(r&7)],
// applied as pre-swizzled GLOBAL source (global_load_lds dest linear) + swizzled ds_read.
// Per K-tile: 2 phases x {ds_read -> barrier -> setprio+16 MFMA -> barrier}; tile t+1's
// 8 GLD16 burst-issued at phase 1, drained by one vmcnt(0) before the tile's last barrier.
__global__ __launch_bounds__(256, 2) void gemm_bt_f16_2ph(const _Float16* __restrict__ A,
                                                          const _Float16* __restrict__ B,
                                                          float* __restrict__ C,
                                                          int M, int N, int K) {
  __shared__ char lds[65536] __attribute__((aligned(16)));
  const int tid = threadIdx.x;
  const int wid = tid >> 6, l = tid & 63;
  const int lr = l & 15, hi = l >> 4;
  const int wm = wid & 1, wn = wid >> 1;  // 2 M-subtiles x 2 N-subtiles of 64

  // XCD-aware swizzle (grids here are multiples of 8)
  int nbx = gridDim.x;
  int bid = blockIdx.y * nbx + blockIdx.x;
  int nwg = nbx * gridDim.y;
  int swz = (nwg & 7) ? bid : ((bid & 7) * (nwg >> 3) + (bid >> 3));
  int bm = (swz / nbx) * 128, bn = (swz % nbx) * 128;

  // staging: 8 GLD16/thread/K-tile (A: 4 chunks of 32 rows; B: 4 chunks).
  // chunk q, thread tid covers LDS row q*32+(tid>>3), col16 tid&7;
  // source col16 = (tid&7) ^ (row&7) = (tid&7) ^ ((tid>>3)&7).
  const int srow = tid >> 3;
  const int csrc = ((tid & 7) ^ ((tid >> 3) & 7)) * 8;  // element offset
  const _Float16* ga[4];
  const _Float16* gb[4];
#pragma unroll
  for (int q = 0; q < 4; ++q) {
    ga[q] = A + (size_t)(bm + q * 32 + srow) * K + csrc;
    gb[q] = B + (size_t)(bn + q * 32 + srow) * K + csrc;
  }
  const int dstA = tid * 16;  // + q*4096
  const int dstB = 16384 + tid * 16;

  // fragment ds addressing (swizzled read): byte = row*128 + ((ks*4+hi)^(row&7))*16,
  // row&7 == lr&7 for all fragment rows (row = base64 + mi*16 + lr).
  int cr[2];
  cr[0] = (hi ^ (lr & 7)) * 16;
  cr[1] = ((4 + hi) ^ (lr & 7)) * 16;
  const int abase = wm * 8192 + lr * 128;          // A region [0,16384)
  const int bbase = 16384 + wn * 8192 + lr * 128;  // B region [16384,32768)

  floatx4 acc[4][4];
#pragma unroll
  for (int i = 0; i < 4; ++i)
#pragma unroll
    for (int j = 0; j < 4; ++j) acc[i][j] = (floatx4){0.f, 0.f, 0.f, 0.f};

  const int NT = K >> 6;
#define STAGE8(tt, pp)                                           \
  {                                                              \
    int kof = (tt) * 64;                                         \
    int pof = (pp) * 32768;                                      \
    _Pragma("unroll") for (int q = 0; q < 4; ++q) {              \
      GLD16(ga[q] + kof, lds + pof + q * 4096 + dstA);           \
      GLD16(gb[q] + kof, lds + pof + q * 4096 + dstB);           \
    }                                                            \
  }

  // prologue: tile 0 -> buf0
  STAGE8(0, 0);
  asm volatile("s_waitcnt vmcnt(0)" ::: "memory");
  SBAR();

  halfx8 af[4][2], bf[2][2];
  for (int t = 0; t < NT; ++t) {
    const char* bufc = lds + (t & 1) * 32768;
    // phase 1: stage tile t+1 (other buffer); read A(mi0-3), B(ni0-1); 16 MFMA (mi0-3 x ni0-1)
    if (t + 1 < NT) STAGE8(t + 1, (t + 1) & 1);
#pragma unroll
    for (int mi = 0; mi < 4; ++mi)
#pragma unroll
      for (int ks = 0; ks < 2; ++ks)
        af[mi][ks] = *(const halfx8*)(bufc + abase + mi * 2048 + cr[ks]);
#pragma unroll
    for (int ni = 0; ni < 2; ++ni)
#pragma unroll
      for (int ks = 0; ks < 2; ++ks)
        bf[ni][ks] = *(const halfx8*)(bufc + bbase + ni * 2048 + cr[ks]);
    SBAR();
    __builtin_amdgcn_s_setprio(1);
#pragma unroll
    for (int mi = 0; mi < 4; ++mi)
#pragma unroll
      for (int ni = 0; ni < 2; ++ni)
#pragma unroll
        for (int ks = 0; ks < 2; ++ks)
          acc[mi][ni] = MFMA16(af[mi][ks], bf[ni][ks], acc[mi][ni]);
    __builtin_amdgcn_s_setprio(0);
    SBAR();
    // phase 2: read B(ni2-3); 16 MFMA (mi0-3 x ni2-3); drain stage before releasing buffers
#pragma unroll
    for (int ni = 0; ni < 2; ++ni)
#pragma unroll
      for (int ks = 0; ks < 2; ++ks)
        bf[ni][ks] = *(const halfx8*)(bufc + bbase + (ni + 2) * 2048 + cr[ks]);
    SBAR();
    __builtin_amdgcn_s_setprio(1);
#pragma unroll
    for (int mi = 0; mi < 4; ++mi)
#pragma unroll
      for (int ni = 0; ni < 2; ++ni)
#pragma unroll
        for (int ks = 0; ks < 2; ++ks)
          acc[mi][ni + 2] = MFMA16(af[mi][ks], bf[ni][ks], acc[mi][ni + 2]);
    __builtin_amdgcn_s_setprio(0);
    asm volatile("s_waitcnt vmcnt(0)" ::: "memory");
    SBAR();
  }
  // epilogue
#pragma unroll
  for (int mi = 0; mi < 4; ++mi)
#pragma unroll
    for (int ni = 0; ni < 4; ++ni) {
      int row0 = bm + wm * 64 + mi * 16 + hi * 4;
      int col = bn + wn * 64 + ni * 16 + lr;
#pragma unroll
      for (int r = 0; r < 4; ++r)
        C[(size_t)(row0 + r) * N + col] = acc[mi][ni][r];
    }
#undef STAGE8
}

// ---------------- gk/b projections -> glog [B,H,S] (= logsigmoid/16), beta [B,H,S] ----------------
__global__ __launch_bounds__(256) void gkb_kernel(const float* __restrict__ X,
                                                  const float* __restrict__ gk_w,
                                                  const float* __restrict__ b_w,
                                                  float* __restrict__ glog,
                                                  float* __restrict__ be) {
  __shared__ float xs[16][260];
  __shared__ float ws[32][260];
  int tid = threadIdx.x;
  int m0 = blockIdx.x * 16;
  int tl = tid >> 4, n0 = tid & 15;
  float acc0 = 0.f, acc1 = 0.f;
  for (int k0 = 0; k0 < HID; k0 += 256) {
#pragma unroll
    for (int i = 0; i < 4; ++i) {
      int F = i * 256 + tid;
      int r = F >> 6, c4 = (F & 63) * 4;
      *(float4*)&xs[r][c4] = *(const float4*)&X[(size_t)(m0 + r) * HID + k0 + c4];
    }
#pragma unroll
    for (int i = 0; i < 8; ++i) {
      int F = i * 256 + tid;
      int r = F >> 6, c4 = (F & 63) * 4;
      const float* src = (r < 16) ? (gk_w + (size_t)r * HID) : (b_w + (size_t)(r - 16) * HID);
      *(float4*)&ws[r][c4] = *(const float4*)&src[k0 + c4];
    }
    __syncthreads();
#pragma unroll 16
    for (int k = 0; k < 256; k += 4) {
      float4 a = *(const float4*)&xs[tl][k];
      float4 w0 = *(const float4*)&ws[n0][k];
      float4 w1 = *(const float4*)&ws[n0 + 16][k];
      acc0 += a.x * w0.x + a.y * w0.y + a.z * w0.z + a.w * w0.w;
      acc1 += a.x * w1.x + a.y * w1.y + a.z * w1.z + a.w * w1.w;
    }
    __syncthreads();
  }
  int m = m0 + tl, b = m >> 11, s = m & (S_LEN - 1);
  float z = acc0;
  float ls = (z >= 0.f) ? -log1pf(expf(-z)) : (z - log1pf(expf(z)));
  size_t oi = (size_t)(b * NH + n0) * S_LEN + s;
  glog[oi] = ls * 0.0625f;
  be[oi] = sigmoidf_(acc1);
}

// ---------------- causal dwconv(K=4)+SiLU, l2norm(q,k), q scale ----------------
// Register-resident sliding window; no LDS, no barriers.
// Block = one 128-channel slot x 32 tokens (4 waves x 8 tokens each).
// Lane l holds channels (cbase+l, cbase+l+64); l2norm = in-wave shfl_xor reduce
// (identical per-lane pairing and butterfly order as the previous version).
// Slots: 0..15 q heads (norm * DK^-0.5), 16..19 k heads (norm), 20..23 v (copy).
__global__ __launch_bounds__(256) void conv_kernel(const float* __restrict__ qkv,
                                                   const float* __restrict__ conv_w,
                                                   float* __restrict__ qn,
                                                   float* __restrict__ kn,
                                                   float* __restrict__ vn) {
  int tile = blockIdx.x, slot = blockIdx.y;
  int w = threadIdx.x >> 6, l = threadIdx.x & 63;
  int m0 = tile * 32 + w * 8;  // global token start for this wave (never crosses batch)
  int b = m0 >> 11, s0 = m0 & (S_LEN - 1);
  int cbase = (slot < 16) ? slot * 128 : (slot < 20 ? 2048 + (slot - 16) * 128
                                                    : 2560 + (slot - 20) * 128);
  int c0 = cbase + l, c1 = c0 + 64;
  float4 wv0 = *(const float4*)&conv_w[c0 * 4];
  float4 wv1 = *(const float4*)&conv_w[c1 * 4];

  // window: a*[0..2] = rows s0-3, s0-2, s0-1 (zero outside batch)
  float a0[3], a1[3];
#pragma unroll
  for (int i = 0; i < 3; ++i) {
    int si = s0 - 3 + i;
    bool v = si >= 0;
    const float* rp = qkv + (size_t)(m0 - 3 + i) * QKV_DIM;
    a0[i] = v ? rp[c0] : 0.f;
    a1[i] = v ? rp[c1] : 0.f;
  }

  float* outp;
  if (slot < 16)      outp = qn + ((size_t)(b * NH + slot) * S_LEN + s0) * DKQ;
  else if (slot < 20) outp = kn + ((size_t)(b * NKV + (slot - 16)) * S_LEN + s0) * DKQ;
  else                outp = vn + ((size_t)(b * NKV + (slot - 20)) * S_LEN + s0) * DVV;

#pragma unroll
  for (int j = 0; j < 8; ++j) {
    const float* rp = qkv + (size_t)(m0 + j) * QKV_DIM;
    float cur0 = rp[c0], cur1 = rp[c1];
    float acc0 = wv0.x * a0[0] + wv0.y * a0[1] + wv0.z * a0[2] + wv0.w * cur0;
    float acc1 = wv1.x * a1[0] + wv1.y * a1[1] + wv1.z * a1[2] + wv1.w * cur1;
    float y0 = acc0 * (1.f / (1.f + __expf(-acc0)));
    float y1 = acc1 * (1.f / (1.f + __expf(-acc1)));
    if (slot < 20) {
      float ss = y0 * y0 + y1 * y1;
#pragma unroll
      for (int off = 1; off < 64; off <<= 1) ss += __shfl_xor(ss, off);
      float scale = rsqrtf(ss + 1e-6f);
      if (slot < 16) scale *= 0.08838834764831845f;  // DK^-0.5
      y0 *= scale;
      y1 *= scale;
    }
    outp[(size_t)j * 128 + l] = y0;
    outp[(size_t)j * 128 + l + 64] = y1;
    a0[0] = a0[1]; a0[1] = a0[2]; a0[2] = cur0;
    a1[0] = a1[1]; a1[1] = a1[2]; a1[2] = cur1;
  }
}

// ---------------- phase A: per (bh, chunk of 64) — fully parallel ----------------
// Computes P,W,D (fwd substitution) then the chunk-local operators:
//   M = gC*I - K̂ᵀW, B = K̂ᵀΔ, E = Q̃ - PW, Oloc = PΔ
// M/E/B -> pA (fp16); Oloc -> obuf (f32, same rows as consumed q).
// LDS plan (80,128 B <= 81,920 -> 2 blocks/CU, 2 waves/SIMD):
//   region A [0,      22528): kh [64][152] f16   -> later Dt [128][88] f16
//   region B [22528,  45056): qh [64][152] f16   -> later Wt [128][88] f16
//   region C [45056,  67584): LT [64][68]  f32   -> later Kt [128][88] f16
//   Ph       [67584,  78848): [64][88] f16
//   sc       [78848,  80128): 5x64 f32
__global__ __launch_bounds__(256, 2) void phaseA_kernel(const float* __restrict__ qn,
                                                        const float* __restrict__ kn,
                                                        const float* __restrict__ vn,
                                                        const float* __restrict__ glog,
                                                        const float* __restrict__ be,
                                                        char* __restrict__ pout,
                                                        float* __restrict__ obuf) {
  __shared__ char smem[80128] __attribute__((aligned(16)));
  _Float16* kh = (_Float16*)smem;
  _Float16* qh = (_Float16*)(smem + 22528);
  float*    LT = (float*)(smem + 45056);
  _Float16* Ph = (_Float16*)(smem + 67584);
  float*    sc_c    = (float*)(smem + 78848);
  float*    sc_beta = sc_c + 64;
  float*    sc_gam  = sc_c + 128;
  float*    sc_bg   = sc_c + 192;
  float*    sc_gcr  = sc_c + 256;
  _Float16* Dt = (_Float16*)smem;            // overlays kh (dead after Kt build)
  _Float16* Wt = (_Float16*)(smem + 22528);  // overlays qh (dead after Eacc init)
  _Float16* Kt = (_Float16*)(smem + 45056);  // overlays LT (dead after fwd subst)

  int u = blockIdx.x;
  int bh = u >> 5, ch = u & 31;
  int t0 = ch * 64;
  int b = bh >> 4, h = bh & 15, kvh = h >> 2;
  const float* qb = qn + ((size_t)bh * S_LEN + t0) * DKQ;
  const float* kb = kn + (((size_t)(b * NKV + kvh)) * S_LEN + t0) * DKQ;
  const float* vb = vn + (((size_t)(b * NKV + kvh)) * S_LEN + t0) * DVV;
  const float* gl = glog + (size_t)bh * S_LEN + t0;
  const float* ber = be + (size_t)bh * S_LEN + t0;
  char* base = pout + (size_t)u * PA_STRIDE;
  _Float16* M_out = (_Float16*)base;
  _Float16* E_out = (_Float16*)(base + 32768);
  _Float16* B_out = (_Float16*)(base + 49152);
  float* ob = obuf + ((size_t)bh * S_LEN + t0) * DVV;

  int tid = threadIdx.x;
  if (tid < 64) {
    float x = gl[tid];
#pragma unroll
    for (int off = 1; off < 64; off <<= 1) {
      float y = __shfl_up(x, off);
      if (tid >= off) x += y;
    }
    sc_c[tid] = x;
  }
#pragma unroll
  for (int i = 0; i < 8; ++i) {
    int idx = i * 256 + tid;
    int t = idx >> 5, d4 = (idx & 31) * 4;
    float4 kv4 = *(const float4*)&kb[(size_t)t * DKQ + d4];
    float4 qv4 = *(const float4*)&qb[(size_t)t * DKQ + d4];
    halfx4 kp, qp;
    kp[0] = (_Float16)kv4.x; kp[1] = (_Float16)kv4.y; kp[2] = (_Float16)kv4.z; kp[3] = (_Float16)kv4.w;
    qp[0] = (_Float16)qv4.x; qp[1] = (_Float16)qv4.y; qp[2] = (_Float16)qv4.z; qp[3] = (_Float16)qv4.w;
    *(halfx4*)&kh[t * 152 + d4] = kp;
    *(halfx4*)&qh[t * 152 + d4] = qp;
  }
  __syncthreads();
  if (tid < 64) {
    float c = sc_c[tid], c63 = sc_c[63];
    float gam = __expf(c);
    float bet = ber[tid];
    sc_gam[tid] = gam; sc_beta[tid] = bet; sc_bg[tid] = bet * gam;
    sc_gcr[tid] = __expf(c63 - c);
  }
  __syncthreads();

  // z init (global loads overlap the MFMA below)
  float z[64];
  {
    const float* src = (tid < 128) ? vb : kb;
    const float* mult = (tid < 128) ? sc_beta : sc_bg;
    int col = tid & 127;
#pragma unroll
    for (int t = 0; t < 64; ++t) z[t] = mult[t] * src[(size_t)t * 128 + col];
  }

  // KK^T (waves 0,1) / QK^T (waves 2,3) -> LT (f32 LDS) / Ph (fp16 LDS)
  int w = tid >> 6, l = tid & 63;
  int lr = l & 15, lk8 = (l >> 4) * 8, q4 = (l >> 4) * 4;
  floatx4 acc[8];
#pragma unroll
  for (int i = 0; i < 8; ++i) acc[i] = (floatx4){0.f, 0.f, 0.f, 0.f};
#pragma unroll
  for (int job = 0; job < 8; ++job) {
    int j2 = w * 8 + job;
    int tm = (j2 & 15) >> 2, tn = j2 & 3;
    const _Float16* Ar = (j2 < 16) ? kh : qh;
#pragma unroll
    for (int kk = 0; kk < 4; ++kk) {
      halfx8 af = *(const halfx8*)&Ar[(tm * 16 + lr) * 152 + kk * 32 + lk8];
      halfx8 bf = *(const halfx8*)&kh[(tn * 16 + lr) * 152 + kk * 32 + lk8];
      acc[job] = MFMA16(af, bf, acc[job]);
    }
  }
#pragma unroll
  for (int job = 0; job < 8; ++job) {
    int j2 = w * 8 + job;
    int tm = (j2 & 15) >> 2, tn = j2 & 3;
    int jcol = tn * 16 + lr;
    float cj = sc_c[jcol];
#pragma unroll
    for (int r = 0; r < 4; ++r) {
      int trow = tm * 16 + q4 + r;
      float val = acc[job][r] * __expf(sc_c[trow] - cj);
      if (j2 < 16) {
        LT[jcol * 68 + trow] = (jcol < trow) ? sc_beta[trow] * val : 0.f;
      } else {
        Ph[trow * 88 + jcol] = (_Float16)((jcol <= trow) ? val : 0.f);
      }
    }
  }
  __syncthreads();

  // forward substitution (I+L) z = x  (reads all of LT)
#pragma unroll
  for (int t = 0; t < 64; ++t) {
    float zt = z[t];
    const int start = ((t + 1) >> 2) << 2;
#pragma unroll
    for (int t2 = start; t2 < 64; t2 += 4) {
      float4 lv = *(const float4*)&LT[t * 68 + t2];
      z[t2 + 0] -= lv.x * zt;
      z[t2 + 1] -= lv.y * zt;
      z[t2 + 2] -= lv.z * zt;
      z[t2 + 3] -= lv.w * zt;
    }
  }
  // Eacc init (reads qh) — must precede the Wt overwrite of qh
  floatx4 Eacc[8];
#pragma unroll
  for (int ni = 0; ni < 8; ++ni)
#pragma unroll
    for (int r = 0; r < 4; ++r) {
      int trow = w * 16 + q4 + r;
      Eacc[ni][r] = sc_gam[trow] * (float)qh[trow * 152 + ni * 16 + lr];
    }
  __syncthreads();  // A: all LT + qh reads complete

  // Kt = K̂ᵀ (gcr-scaled) into ex-LT region; contiguous-t halfx8 stores
  {
    int d = tid >> 1, tb = (tid & 1) * 32;
#pragma unroll
    for (int j = 0; j < 4; ++j) {
      halfx8 kv;
#pragma unroll
      for (int r = 0; r < 8; ++r) {
        int t = tb + j * 8 + r;
        kv[r] = (_Float16)(sc_gcr[t] * (float)kh[t * 152 + d]);
      }
      *(halfx8*)&Kt[d * 88 + tb + j * 8] = kv;
    }
  }
  // Wt = -Wᵀ into ex-qh region (safe after barrier A)
  if (tid >= 128) {
    int col = tid & 127;
#pragma unroll
    for (int t = 0; t < 64; t += 8) {
      halfx8 wv;
#pragma unroll
      for (int r = 0; r < 8; ++r) wv[r] = (_Float16)(-z[t + r]);
      *(halfx8*)&Wt[col * 88 + t] = wv;
    }
  }
  __syncthreads();  // B: all kh reads (Kt build) complete
  // Dt = Δᵀ into ex-kh region
  if (tid < 128) {
    int col = tid & 127;
#pragma unroll
    for (int t = 0; t < 64; t += 8) {
      halfx8 dv;
#pragma unroll
      for (int r = 0; r < 8; ++r) dv[r] = (_Float16)z[t + r];
      *(halfx8*)&Dt[col * 88 + t] = dv;
    }
  }
  __syncthreads();  // C: Kt/Wt/Dt visible

  // builds: wave w -> M/B row-tiles {w*32, w*32+16}; E/Oloc t-tile w
  floatx4 Macc[2][8], Bacc[2][8], Oacc[8];
  float gC = __expf(sc_c[63]);
#pragma unroll
  for (int mi = 0; mi < 2; ++mi)
#pragma unroll
    for (int ni = 0; ni < 8; ++ni) {
#pragma unroll
      for (int r = 0; r < 4; ++r)
        Macc[mi][ni][r] = ((w * 32 + mi * 16 + q4 + r) == (ni * 16 + lr)) ? gC : 0.f;
      Bacc[mi][ni] = (floatx4){0.f, 0.f, 0.f, 0.f};
    }
#pragma unroll
  for (int ni = 0; ni < 8; ++ni) Oacc[ni] = (floatx4){0.f, 0.f, 0.f, 0.f};
#pragma unroll
  for (int ks = 0; ks < 2; ++ks) {
    halfx8 ka0 = *(const halfx8*)&Kt[(w * 32 + lr) * 88 + ks * 32 + lk8];
    halfx8 ka1 = *(const halfx8*)&Kt[(w * 32 + 16 + lr) * 88 + ks * 32 + lk8];
    halfx8 pa = *(const halfx8*)&Ph[(w * 16 + lr) * 88 + ks * 32 + lk8];
#pragma unroll
    for (int ni = 0; ni < 8; ++ni) {
      halfx8 wb = *(const halfx8*)&Wt[(ni * 16 + lr) * 88 + ks * 32 + lk8];
      halfx8 db = *(const halfx8*)&Dt[(ni * 16 + lr) * 88 + ks * 32 + lk8];
      Macc[0][ni] = MFMA16(ka0, wb, Macc[0][ni]);
      Macc[1][ni] = MFMA16(ka1, wb, Macc[1][ni]);
      Bacc[0][ni] = MFMA16(ka0, db, Bacc[0][ni]);
      Bacc[1][ni] = MFMA16(ka1, db, Bacc[1][ni]);
      Eacc[ni] = MFMA16(pa, wb, Eacc[ni]);
      Oacc[ni] = MFMA16(pa, db, Oacc[ni]);
    }
  }
  // outputs
#pragma unroll
  for (int mi = 0; mi < 2; ++mi)
#pragma unroll
    for (int ni = 0; ni < 8; ++ni)
#pragma unroll
      for (int r = 0; r < 4; ++r) {
        int row = w * 32 + mi * 16 + q4 + r;
        M_out[row * 128 + ni * 16 + lr] = (_Float16)Macc[mi][ni][r];
        B_out[ni * 2048 + row * 16 + lr] = (_Float16)Bacc[mi][ni][r];
      }
#pragma unroll
  for (int ni = 0; ni < 8; ++ni)
#pragma unroll
    for (int r = 0; r < 4; ++r) {
      int trow = w * 16 + q4 + r;
      E_out[trow * 128 + ni * 16 + lr] = (_Float16)Eacc[ni][r];
      ob[(size_t)trow * 128 + ni * 16 + lr] = Oacc[ni][r];
    }
}

// ---------------- phase B: 256 blocks (32 bh x 8 vgroups), serial over 32 chunks ----------------
// Per chunk: S <- M*S + B ; O = E*S + Oloc.
// Key fact: each wave's MFMA fragments use ONLY its own rows of M (w*32..+31) and E
// (w*16..+15) — no cross-wave sharing. So M/E are loaded DIRECTLY from global into the
// halfx8 MFMA operand registers (16B-aligned), double-buffered in two explicit register
// sets (static indexing). Only St (S^T, cross-wave) lives in LDS (9.7 KB). One barrier
// per chunk orders St[cur] visibility; global prefetch of chunk c+1 overlaps the MFMAs
// via per-register counted vmcnt. Values and MFMA order identical to the LDS version.
__global__ __launch_bounds__(256, 1) void phaseB_kernel(const char* __restrict__ pin,
                                                        float* __restrict__ obuf) {
  __shared__ _Float16 St[2][16 * 152];

  int bh = blockIdx.x & 31, vg = blockIdx.x >> 5;  // same-bh blocks land on same XCD
  int tid = threadIdx.x, w = tid >> 6, l = tid & 63;
  int lr = l & 15, lk8 = (l >> 4) * 8, q4 = (l >> 4) * 4;
  const char* ub0 = pin + (size_t)(bh * 32) * PA_STRIDE;
  float* ob_base = obuf + (size_t)bh * S_LEN * DVV + vg * 16;

  halfx8 MaA[2][4], EaA[4], MaB[2][4], EaB[4];
  float BcA[2][4], OcA[4], BcB[2][4], OcB[4];

#define LOADSET(c, Ma_, Ea_, Bc_, Oc_)                                             \
  {                                                                                \
    const char* un = ub0 + (size_t)(c) * PA_STRIDE;                                \
    const _Float16* Mg = (const _Float16*)un;                                      \
    const _Float16* Eg = (const _Float16*)(un + 32768);                            \
    const _Float16* Bg = (const _Float16*)(un + 49152) + vg * 2048;                \
    _Pragma("unroll") for (int ks = 0; ks < 4; ++ks) {                             \
      Ma_[0][ks] = *(const halfx8*)&Mg[(w * 32 + lr) * 128 + ks * 32 + lk8];       \
      Ma_[1][ks] = *(const halfx8*)&Mg[(w * 32 + 16 + lr) * 128 + ks * 32 + lk8];  \
      Ea_[ks] = *(const halfx8*)&Eg[(w * 16 + lr) * 128 + ks * 32 + lk8];          \
    }                                                                              \
    _Pragma("unroll") for (int mi = 0; mi < 2; ++mi)                               \
      _Pragma("unroll") for (int r = 0; r < 4; ++r)                                \
        Bc_[mi][r] = (float)Bg[(w * 32 + mi * 16 + q4 + r) * 16 + lr];             \
    _Pragma("unroll") for (int r = 0; r < 4; ++r)                                  \
      Oc_[r] = ob_base[(size_t)((c) * 64 + w * 16 + q4 + r) * DVV + lr];           \
  }

#define STEP(c, Ma_, Ea_, Bc_, Oc_, Mn_, En_, Bn_, On_)                            \
  {                                                                                \
    __builtin_amdgcn_s_barrier(); /* St[(c)&1] writes visible */                   \
    if ((c) + 1 < 32) LOADSET((c) + 1, Mn_, En_, Bn_, On_);                        \
    const int cur = (c) & 1, nxt = cur ^ 1;                                        \
    floatx4 Sn0 = {Bc_[0][0], Bc_[0][1], Bc_[0][2], Bc_[0][3]};                    \
    floatx4 Sn1 = {Bc_[1][0], Bc_[1][1], Bc_[1][2], Bc_[1][3]};                    \
    floatx4 Oa = {Oc_[0], Oc_[1], Oc_[2], Oc_[3]};                                 \
    _Pragma("unroll") for (int ks = 0; ks < 4; ++ks) {                             \
      halfx8 sf = *(const halfx8*)&St[cur][lr * 152 + ks * 32 + lk8];              \
      Sn0 = MFMA16(Ma_[0][ks], sf, Sn0);                                           \
      Sn1 = MFMA16(Ma_[1][ks], sf, Sn1);                                           \
      Oa = MFMA16(Ea_[ks], sf, Oa);                                                \
    }                                                                              \
    float* obr = ob_base + (size_t)(c) * 64 * DVV;                                 \
    _Pragma("unroll") for (int r = 0; r < 4; ++r)                                  \
      obr[(size_t)(w * 16 + q4 + r) * DVV + lr] = Oa[r];                           \
    _Pragma("unroll") for (int mi = 0; mi < 2; ++mi) {                             \
      halfx4 sv;                                                                   \
      floatx4 Sm = mi ? Sn1 : Sn0;                                                 \
      _Pragma("unroll") for (int r = 0; r < 4; ++r) sv[r] = (_Float16)Sm[r];       \
      *(halfx4*)&St[nxt][lr * 152 + w * 32 + mi * 16 + q4] = sv;                   \
    }                                                                              \
    asm volatile("s_waitcnt lgkmcnt(0)" ::: "memory"); /* St writes retired */     \
  }

  // prologue: chunk 0 operands + S_0 = 0
  LOADSET(0, MaA, EaA, BcA, OcA);
  {
    halfx4 z4;
    z4[0] = (_Float16)0.f; z4[1] = (_Float16)0.f; z4[2] = (_Float16)0.f; z4[3] = (_Float16)0.f;
#pragma unroll
    for (int mi = 0; mi < 2; ++mi)
      *(halfx4*)&St[0][lr * 152 + w * 32 + mi * 16 + q4] = z4;
  }
  asm volatile("s_waitcnt lgkmcnt(0)" ::: "memory");

  for (int c2 = 0; c2 < 16; ++c2) {
    STEP(2 * c2,     MaA, EaA, BcA, OcA, MaB, EaB, BcB, OcB);
    STEP(2 * c2 + 1, MaB, EaB, BcB, OcB, MaA, EaA, BcA, OcA);
  }
#undef LOADSET
#undef STEP
}

// ---------------- per-head RMSNorm * out_norm_w * silu(g) -> og fp16 [M, H*DV] ----------------
__global__ __launch_bounds__(256) void normgate_kernel(const float* __restrict__ o_buf,
                                                       const float* __restrict__ g_buf,
                                                       const float* __restrict__ nw,
                                                       _Float16* __restrict__ og) {
  int gid = blockIdx.x * 4 + (threadIdx.x >> 6);
  int lane = threadIdx.x & 63;
  int m = gid >> 4, h = gid & 15;
  int b = m >> 11, s = m & (S_LEN - 1);
  const float* orow = o_buf + ((size_t)(b * NH + h) * S_LEN + s) * DVV;
  float o0 = orow[lane], o1 = orow[lane + 64];
  float ss = o0 * o0 + o1 * o1;
#pragma unroll
  for (int off = 1; off < 64; off <<= 1) ss += __shfl_xor(ss, off);
  float r = rsqrtf(ss * (1.f / 128.f) + 1e-5f);
  size_t gi = (size_t)m * HID + h * DVV;
  float g0 = g_buf[gi + lane], g1 = g_buf[gi + lane + 64];
  og[gi + lane] = (_Float16)(o0 * r * nw[lane] * (g0 * sigmoidf_(g0)));
  og[gi + lane + 64] = (_Float16)(o1 * r * nw[lane + 64] * (g1 * sigmoidf_(g1)));
}

extern "C" void kernel_launch(void* const* d_in, const int* in_sizes, int n_in,
                              void* d_out, int out_size, void* d_ws, size_t ws_size,
                              hipStream_t stream) {
  const float* X      = (const float*)d_in[0];
  const float* qkv_w  = (const float*)d_in[1];
  const float* g_w    = (const float*)d_in[2];
  const float* b_w    = (const float*)d_in[3];
  const float* gk_w   = (const float*)d_in[4];
  const float* conv_w = (const float*)d_in[5];
  const float* norm_w = (const float*)d_in[6];
  const float* o_w    = (const float*)d_in[7];
  float* out = (float*)d_out;

  char* ws = (char*)d_ws;
  // lifetimes: qkv_buf [gemm_qkv..conv]; g_buf [gemm_g..normgate]; pA [phaseA..phaseB];
  // X16 [cvt..gemm_g]; qw16 [cvt..gemm_qkv]; gw16 [cvt..gemm_g]; og16 [normgate..gemm_out]
  float* qkv_buf   = (float*)(ws);                    // [0, 50331648)
  float* g_buf     = (float*)(ws);                    // [0, 33554432)
  _Float16* ow16   = (_Float16*)(ws + 33554432);      // [33554432, 41943040) written after conv
  float* glog      = (float*)(ws + 41943040);         // written after conv (qkv tail dead)
  float* be        = (float*)(ws + 42205184);
  float* qn        = (float*)(ws + 50331648);         // [50331648, 83886080); obuf reuses
  float* kn        = (float*)(ws + 83886080);         // 8 MiB
  float* vn        = (float*)(ws + 92274688);         // 8 MiB
  _Float16* X16    = (_Float16*)(ws + 100663296);     // 16 MiB, dead before phaseA
  _Float16* qw16   = (_Float16*)(ws + 117440512);     // 12 MiB, dead after gemm_qkv
  _Float16* gw16   = (_Float16*)(ws + 130023424);     // 8 MiB, dead after gemm_g
  char*  pA        = (char*)(ws + 100663296);         // 80 MiB [100663296, 184549376)
  _Float16* og16   = (_Float16*)(ws + 100663296);     // reuse pA after phaseB
  float* o_buf     = qn;

  dim3 blk(256);
  cvt_f16<<<dim3(4096), blk, 0, stream>>>(X, X16, 1048576);
  cvt_f16<<<dim3(3072), blk, 0, stream>>>(qkv_w, qw16, 786432);
  cvt_f16<<<dim3(2048), blk, 0, stream>>>(g_w, gw16, 524288);
  // 1) qkv projection
  gemm_bt_f16_2ph<<<dim3(QKV_DIM / 128, M_TOK / 128), blk, 0, stream>>>(X16, qw16, qkv_buf, M_TOK, QKV_DIM, HID);
  // 2) conv + silu + l2norm (consumes qkv_buf); 128 token-tiles x 24 channel slots
  conv_kernel<<<dim3(M_TOK / 32, 24), blk, 0, stream>>>(qkv_buf, conv_w, qn, kn, vn);
  // 3) glog/beta + o_w cvt (into freed qkv region)
  gkb_kernel<<<dim3(M_TOK / 16), blk, 0, stream>>>(X, gk_w, b_w, glog, be);
  cvt_f16<<<dim3(2048), blk, 0, stream>>>(o_w, ow16, 524288);
  // 4) g projection (overwrites qkv_buf head; X16/gw16 die here)
  gemm_bt_f16_2ph<<<dim3(HID / 128, M_TOK / 128), blk, 0, stream>>>(X16, gw16, g_buf, M_TOK, HID, HID);
  // 5) chunked gated delta rule
  phaseA_kernel<<<dim3(1024), blk, 0, stream>>>(qn, kn, vn, glog, be, pA, o_buf);
  phaseB_kernel<<<dim3(256), blk, 0, stream>>>(pA, o_buf);
  // 6) RMSNorm + gate -> og fp16 (pA dead)
  normgate_kernel<<<dim3(M_TOK * NH / 4), blk, 0, stream>>>(o_buf, g_buf, norm_w, og16);
  // 7) output projection
  gemm_bt_f16_2ph<<<dim3(HID / 128, M_TOK / 128), blk, 0, stream>>>(og16, ow16, out, M_TOK, HID, HID);
}

// Round 8
// 429.956 us; speedup vs baseline: 1.0576x; 1.0576x over previous
//
#include <hip/hip_runtime.h>
#include <math.h>

#define S_LEN 2048
#define BATCH 2
#define NH 16
#define NKV 4
#define DKQ 128
#define DVV 128
#define HID 2048
#define QKV_DIM 3072
#define M_TOK 4096

typedef _Float16 halfx8 __attribute__((ext_vector_type(8)));
typedef _Float16 halfx4 __attribute__((ext_vector_type(4)));
typedef float floatx4 __attribute__((ext_vector_type(4)));

#define AS1 __attribute__((address_space(1)))
#define AS3 __attribute__((address_space(3)))
#define GLD16(gp, lp) __builtin_amdgcn_global_load_lds((AS1 const void*)(gp), (AS3 void*)(lp), 16, 0, 0)
#define MFMA16(a, b, c) __builtin_amdgcn_mfma_f32_16x16x32_f16(a, b, c, 0, 0, 0)
#define SBAR() asm volatile("s_barrier" ::: "memory")

#define PA_STRIDE 81920  // per (bh,chunk): M 32768 | E 16384 | B 32768 (8 panels of [128][16])

__device__ __forceinline__ float sigmoidf_(float x) { return 1.f / (1.f + __expf(-x)); }

// ---------------- f32 -> f16 convert (8 elems/thread) ----------------
__global__ __launch_bounds__(256) void cvt_f16(const float* __restrict__ in,
                                               _Float16* __restrict__ out, int n8) {
  int i = blockIdx.x * 256 + threadIdx.x;
  if (i >= n8) return;
  const float4* p = (const float4*)in;
  float4 a = p[2 * (size_t)i], b = p[2 * (size_t)i + 1];
  halfx8 o;
  o[0] = (_Float16)a.x; o[1] = (_Float16)a.y; o[2] = (_Float16)a.z; o[3] = (_Float16)a.w;
  o[4] = (_Float16)b.x; o[5] = (_Float16)b.y; o[6] = (_Float16)b.z; o[7] = (_Float16)b.w;
  *(halfx8*)(out + (size_t)i * 8) = o;
}

// ---------------- fp16 MFMA GEMM NT, 128x128 tile, BK=64, 2-phase schedule ----------------
// C[M,N] f32 = A[M,K] * B[N,K]^T.  256 threads = 4 waves (2M x 2N), per-wave C 64x64.
// LDS 64KiB (2 blocks/CU -> independent barrier groups overlap each other's drains):
//   2 K-tile buffers x (A 128x64 + B 128x64) f16.
// Full 3-bit column swizzle (verified conflict-free in R4): LDS[r][c16] = global[r][c16^(r&7)],
// applied as pre-swizzled GLOBAL source (global_load_lds dest linear) + swizzled ds_read.
// Per K-tile: 2 phases x {ds_read -> barrier -> setprio+16 MFMA -> barrier}; tile t+1's
// 8 GLD16 burst-issued at phase 1, drained by one vmcnt(0) before the tile's last barrier.
__global__ __launch_bounds__(256, 2) void gemm_bt_f16_2ph(const _Float16* __restrict__ A,
                                                          const _Float16* __restrict__ B,
                                                          float* __restrict__ C,
                                                          int M, int N, int K) {
  __shared__ char lds[65536] __attribute__((aligned(16)));
  const int tid = threadIdx.x;
  const int wid = tid >> 6, l = tid & 63;
  const int lr = l & 15, hi = l >> 4;
  const int wm = wid & 1, wn = wid >> 1;  // 2 M-subtiles x 2 N-subtiles of 64

  // XCD-aware swizzle (grids here are multiples of 8)
  int nbx = gridDim.x;
  int bid = blockIdx.y * nbx + blockIdx.x;
  int nwg = nbx * gridDim.y;
  int swz = (nwg & 7) ? bid : ((bid & 7) * (nwg >> 3) + (bid >> 3));
  int bm = (swz / nbx) * 128, bn = (swz % nbx) * 128;

  // staging: 8 GLD16/thread/K-tile (A: 4 chunks of 32 rows; B: 4 chunks).
  // chunk q, thread tid covers LDS row q*32+(tid>>3), col16 tid&7;
  // source col16 = (tid&7) ^ (row&7) = (tid&7) ^ ((tid>>3)&7).
  const int srow = tid >> 3;
  const int csrc = ((tid & 7) ^ ((tid >> 3) & 7)) * 8;  // element offset
  const _Float16* ga[4];
  const _Float16* gb[4];
#pragma unroll
  for (int q = 0; q < 4; ++q) {
    ga[q] = A + (size_t)(bm + q * 32 + srow) * K + csrc;
    gb[q] = B + (size_t)(bn + q * 32 + srow) * K + csrc;
  }
  const int dstA = tid * 16;  // + q*4096
  const int dstB = 16384 + tid * 16;

  // fragment ds addressing (swizzled read): byte = row*128 + ((ks*4+hi)^(row&7))*16,
  // row&7 == lr&7 for all fragment rows (row = base64 + mi*16 + lr).
  int cr[2];
  cr[0] = (hi ^ (lr & 7)) * 16;
  cr[1] = ((4 + hi) ^ (lr & 7)) * 16;
  const int abase = wm * 8192 + lr * 128;          // A region [0,16384)
  const int bbase = 16384 + wn * 8192 + lr * 128;  // B region [16384,32768)

  floatx4 acc[4][4];
#pragma unroll
  for (int i = 0; i < 4; ++i)
#pragma unroll
    for (int j = 0; j < 4; ++j) acc[i][j] = (floatx4){0.f, 0.f, 0.f, 0.f};

  const int NT = K >> 6;
#define STAGE8(tt, pp)                                           \
  {                                                              \
    int kof = (tt) * 64;                                         \
    int pof = (pp) * 32768;                                      \
    _Pragma("unroll") for (int q = 0; q < 4; ++q) {              \
      GLD16(ga[q] + kof, lds + pof + q * 4096 + dstA);           \
      GLD16(gb[q] + kof, lds + pof + q * 4096 + dstB);           \
    }                                                            \
  }

  // prologue: tile 0 -> buf0
  STAGE8(0, 0);
  asm volatile("s_waitcnt vmcnt(0)" ::: "memory");
  SBAR();

  halfx8 af[4][2], bf[2][2];
  for (int t = 0; t < NT; ++t) {
    const char* bufc = lds + (t & 1) * 32768;
    // phase 1: stage tile t+1 (other buffer); read A(mi0-3), B(ni0-1); 16 MFMA (mi0-3 x ni0-1)
    if (t + 1 < NT) STAGE8(t + 1, (t + 1) & 1);
#pragma unroll
    for (int mi = 0; mi < 4; ++mi)
#pragma unroll
      for (int ks = 0; ks < 2; ++ks)
        af[mi][ks] = *(const halfx8*)(bufc + abase + mi * 2048 + cr[ks]);
#pragma unroll
    for (int ni = 0; ni < 2; ++ni)
#pragma unroll
      for (int ks = 0; ks < 2; ++ks)
        bf[ni][ks] = *(const halfx8*)(bufc + bbase + ni * 2048 + cr[ks]);
    SBAR();
    __builtin_amdgcn_s_setprio(1);
#pragma unroll
    for (int mi = 0; mi < 4; ++mi)
#pragma unroll
      for (int ni = 0; ni < 2; ++ni)
#pragma unroll
        for (int ks = 0; ks < 2; ++ks)
          acc[mi][ni] = MFMA16(af[mi][ks], bf[ni][ks], acc[mi][ni]);
    __builtin_amdgcn_s_setprio(0);
    SBAR();
    // phase 2: read B(ni2-3); 16 MFMA (mi0-3 x ni2-3); drain stage before releasing buffers
#pragma unroll
    for (int ni = 0; ni < 2; ++ni)
#pragma unroll
      for (int ks = 0; ks < 2; ++ks)
        bf[ni][ks] = *(const halfx8*)(bufc + bbase + (ni + 2) * 2048 + cr[ks]);
    SBAR();
    __builtin_amdgcn_s_setprio(1);
#pragma unroll
    for (int mi = 0; mi < 4; ++mi)
#pragma unroll
      for (int ni = 0; ni < 2; ++ni)
#pragma unroll
        for (int ks = 0; ks < 2; ++ks)
          acc[mi][ni + 2] = MFMA16(af[mi][ks], bf[ni][ks], acc[mi][ni + 2]);
    __builtin_amdgcn_s_setprio(0);
    asm volatile("s_waitcnt vmcnt(0)" ::: "memory");
    SBAR();
  }
  // epilogue
#pragma unroll
  for (int mi = 0; mi < 4; ++mi)
#pragma unroll
    for (int ni = 0; ni < 4; ++ni) {
      int row0 = bm + wm * 64 + mi * 16 + hi * 4;
      int col = bn + wn * 64 + ni * 16 + lr;
#pragma unroll
      for (int r = 0; r < 4; ++r)
        C[(size_t)(row0 + r) * N + col] = acc[mi][ni][r];
    }
#undef STAGE8
}

// ---------------- gk/b projections -> glog [B,H,S] (= logsigmoid/16), beta [B,H,S] ----------------
__global__ __launch_bounds__(256) void gkb_kernel(const float* __restrict__ X,
                                                  const float* __restrict__ gk_w,
                                                  const float* __restrict__ b_w,
                                                  float* __restrict__ glog,
                                                  float* __restrict__ be) {
  __shared__ float xs[16][260];
  __shared__ float ws[32][260];
  int tid = threadIdx.x;
  int m0 = blockIdx.x * 16;
  int tl = tid >> 4, n0 = tid & 15;
  float acc0 = 0.f, acc1 = 0.f;
  for (int k0 = 0; k0 < HID; k0 += 256) {
#pragma unroll
    for (int i = 0; i < 4; ++i) {
      int F = i * 256 + tid;
      int r = F >> 6, c4 = (F & 63) * 4;
      *(float4*)&xs[r][c4] = *(const float4*)&X[(size_t)(m0 + r) * HID + k0 + c4];
    }
#pragma unroll
    for (int i = 0; i < 8; ++i) {
      int F = i * 256 + tid;
      int r = F >> 6, c4 = (F & 63) * 4;
      const float* src = (r < 16) ? (gk_w + (size_t)r * HID) : (b_w + (size_t)(r - 16) * HID);
      *(float4*)&ws[r][c4] = *(const float4*)&src[k0 + c4];
    }
    __syncthreads();
#pragma unroll 16
    for (int k = 0; k < 256; k += 4) {
      float4 a = *(const float4*)&xs[tl][k];
      float4 w0 = *(const float4*)&ws[n0][k];
      float4 w1 = *(const float4*)&ws[n0 + 16][k];
      acc0 += a.x * w0.x + a.y * w0.y + a.z * w0.z + a.w * w0.w;
      acc1 += a.x * w1.x + a.y * w1.y + a.z * w1.z + a.w * w1.w;
    }
    __syncthreads();
  }
  int m = m0 + tl, b = m >> 11, s = m & (S_LEN - 1);
  float z = acc0;
  float ls = (z >= 0.f) ? -log1pf(expf(-z)) : (z - log1pf(expf(z)));
  size_t oi = (size_t)(b * NH + n0) * S_LEN + s;
  glog[oi] = ls * 0.0625f;
  be[oi] = sigmoidf_(acc1);
}

// ---------------- causal dwconv(K=4)+SiLU, l2norm(q,k), q scale ----------------
// Register-resident sliding window; no LDS, no barriers.
// Block = one 128-channel slot x 32 tokens (4 waves x 8 tokens each).
// Lane l holds channels (cbase+l, cbase+l+64); l2norm = in-wave shfl_xor reduce
// (identical per-lane pairing and butterfly order as the previous version).
// Slots: 0..15 q heads (norm * DK^-0.5), 16..19 k heads (norm), 20..23 v (copy).
__global__ __launch_bounds__(256) void conv_kernel(const float* __restrict__ qkv,
                                                   const float* __restrict__ conv_w,
                                                   float* __restrict__ qn,
                                                   float* __restrict__ kn,
                                                   float* __restrict__ vn) {
  int tile = blockIdx.x, slot = blockIdx.y;
  int w = threadIdx.x >> 6, l = threadIdx.x & 63;
  int m0 = tile * 32 + w * 8;  // global token start for this wave (never crosses batch)
  int b = m0 >> 11, s0 = m0 & (S_LEN - 1);
  int cbase = (slot < 16) ? slot * 128 : (slot < 20 ? 2048 + (slot - 16) * 128
                                                    : 2560 + (slot - 20) * 128);
  int c0 = cbase + l, c1 = c0 + 64;
  float4 wv0 = *(const float4*)&conv_w[c0 * 4];
  float4 wv1 = *(const float4*)&conv_w[c1 * 4];

  // window: a*[0..2] = rows s0-3, s0-2, s0-1 (zero outside batch)
  float a0[3], a1[3];
#pragma unroll
  for (int i = 0; i < 3; ++i) {
    int si = s0 - 3 + i;
    bool v = si >= 0;
    const float* rp = qkv + (size_t)(m0 - 3 + i) * QKV_DIM;
    a0[i] = v ? rp[c0] : 0.f;
    a1[i] = v ? rp[c1] : 0.f;
  }

  float* outp;
  if (slot < 16)      outp = qn + ((size_t)(b * NH + slot) * S_LEN + s0) * DKQ;
  else if (slot < 20) outp = kn + ((size_t)(b * NKV + (slot - 16)) * S_LEN + s0) * DKQ;
  else                outp = vn + ((size_t)(b * NKV + (slot - 20)) * S_LEN + s0) * DVV;

#pragma unroll
  for (int j = 0; j < 8; ++j) {
    const float* rp = qkv + (size_t)(m0 + j) * QKV_DIM;
    float cur0 = rp[c0], cur1 = rp[c1];
    float acc0 = wv0.x * a0[0] + wv0.y * a0[1] + wv0.z * a0[2] + wv0.w * cur0;
    float acc1 = wv1.x * a1[0] + wv1.y * a1[1] + wv1.z * a1[2] + wv1.w * cur1;
    float y0 = acc0 * (1.f / (1.f + __expf(-acc0)));
    float y1 = acc1 * (1.f / (1.f + __expf(-acc1)));
    if (slot < 20) {
      float ss = y0 * y0 + y1 * y1;
#pragma unroll
      for (int off = 1; off < 64; off <<= 1) ss += __shfl_xor(ss, off);
      float scale = rsqrtf(ss + 1e-6f);
      if (slot < 16) scale *= 0.08838834764831845f;  // DK^-0.5
      y0 *= scale;
      y1 *= scale;
    }
    outp[(size_t)j * 128 + l] = y0;
    outp[(size_t)j * 128 + l + 64] = y1;
    a0[0] = a0[1]; a0[1] = a0[2]; a0[2] = cur0;
    a1[0] = a1[1]; a1[1] = a1[2]; a1[2] = cur1;
  }
}

// ---------------- phase A: per (bh, chunk of 64) — fully parallel ----------------
// Computes P,W,D (fwd substitution) then the chunk-local operators:
//   M = gC*I - K̂ᵀW, B = K̂ᵀΔ, E = Q̃ - PW, Oloc = PΔ
// M/E/B -> pA (fp16); Oloc -> obuf (f32, same rows as consumed q).
// LDS plan (80,128 B <= 81,920 -> 2 blocks/CU, 2 waves/SIMD):
//   region A [0,      22528): kh [64][152] f16   -> later Dt [128][88] f16
//   region B [22528,  45056): qh [64][152] f16   -> later Wt [128][88] f16
//   region C [45056,  67584): LT [64][68]  f32   -> later Kt [128][88] f16
//   Ph       [67584,  78848): [64][88] f16
//   sc       [78848,  80128): 5x64 f32
__global__ __launch_bounds__(256, 2) void phaseA_kernel(const float* __restrict__ qn,
                                                        const float* __restrict__ kn,
                                                        const float* __restrict__ vn,
                                                        const float* __restrict__ glog,
                                                        const float* __restrict__ be,
                                                        char* __restrict__ pout,
                                                        float* __restrict__ obuf) {
  __shared__ char smem[80128] __attribute__((aligned(16)));
  _Float16* kh = (_Float16*)smem;
  _Float16* qh = (_Float16*)(smem + 22528);
  float*    LT = (float*)(smem + 45056);
  _Float16* Ph = (_Float16*)(smem + 67584);
  float*    sc_c    = (float*)(smem + 78848);
  float*    sc_beta = sc_c + 64;
  float*    sc_gam  = sc_c + 128;
  float*    sc_bg   = sc_c + 192;
  float*    sc_gcr  = sc_c + 256;
  _Float16* Dt = (_Float16*)smem;            // overlays kh (dead after Kt build)
  _Float16* Wt = (_Float16*)(smem + 22528);  // overlays qh (dead after Eacc init)
  _Float16* Kt = (_Float16*)(smem + 45056);  // overlays LT (dead after fwd subst)

  int u = blockIdx.x;
  int bh = u >> 5, ch = u & 31;
  int t0 = ch * 64;
  int b = bh >> 4, h = bh & 15, kvh = h >> 2;
  const float* qb = qn + ((size_t)bh * S_LEN + t0) * DKQ;
  const float* kb = kn + (((size_t)(b * NKV + kvh)) * S_LEN + t0) * DKQ;
  const float* vb = vn + (((size_t)(b * NKV + kvh)) * S_LEN + t0) * DVV;
  const float* gl = glog + (size_t)bh * S_LEN + t0;
  const float* ber = be + (size_t)bh * S_LEN + t0;
  char* base = pout + (size_t)u * PA_STRIDE;
  _Float16* M_out = (_Float16*)base;
  _Float16* E_out = (_Float16*)(base + 32768);
  _Float16* B_out = (_Float16*)(base + 49152);
  float* ob = obuf + ((size_t)bh * S_LEN + t0) * DVV;

  int tid = threadIdx.x;
  // scan + all sc_* in one wave-0 pass (c63 via shfl), single barrier below
  if (tid < 64) {
    float x = gl[tid];
#pragma unroll
    for (int off = 1; off < 64; off <<= 1) {
      float y = __shfl_up(x, off);
      if (tid >= off) x += y;
    }
    sc_c[tid] = x;
    float c63 = __shfl(x, 63);
    float gam = __expf(x);
    float bet = ber[tid];
    sc_gam[tid] = gam; sc_beta[tid] = bet; sc_bg[tid] = bet * gam;
    sc_gcr[tid] = __expf(c63 - x);
  }
#pragma unroll
  for (int i = 0; i < 8; ++i) {
    int idx = i * 256 + tid;
    int t = idx >> 5, d4 = (idx & 31) * 4;
    float4 kv4 = *(const float4*)&kb[(size_t)t * DKQ + d4];
    float4 qv4 = *(const float4*)&qb[(size_t)t * DKQ + d4];
    halfx4 kp, qp;
    kp[0] = (_Float16)kv4.x; kp[1] = (_Float16)kv4.y; kp[2] = (_Float16)kv4.z; kp[3] = (_Float16)kv4.w;
    qp[0] = (_Float16)qv4.x; qp[1] = (_Float16)qv4.y; qp[2] = (_Float16)qv4.z; qp[3] = (_Float16)qv4.w;
    *(halfx4*)&kh[t * 152 + d4] = kp;
    *(halfx4*)&qh[t * 152 + d4] = qp;
  }
  __syncthreads();

  // z init (global loads overlap the MFMA below)
  float z[64];
  {
    const float* src = (tid < 128) ? vb : kb;
    const float* mult = (tid < 128) ? sc_beta : sc_bg;
    int col = tid & 127;
#pragma unroll
    for (int t = 0; t < 64; ++t) z[t] = mult[t] * src[(size_t)t * 128 + col];
  }

  // KK^T (waves 0,1) / QK^T (waves 2,3) -> LT (f32 LDS) / Ph (fp16 LDS)
  int w = tid >> 6, l = tid & 63;
  int lr = l & 15, lk8 = (l >> 4) * 8, q4 = (l >> 4) * 4;
  floatx4 acc[8];
#pragma unroll
  for (int i = 0; i < 8; ++i) acc[i] = (floatx4){0.f, 0.f, 0.f, 0.f};
#pragma unroll
  for (int job = 0; job < 8; ++job) {
    int j2 = w * 8 + job;
    int tm = (j2 & 15) >> 2, tn = j2 & 3;
    const _Float16* Ar = (j2 < 16) ? kh : qh;
#pragma unroll
    for (int kk = 0; kk < 4; ++kk) {
      halfx8 af = *(const halfx8*)&Ar[(tm * 16 + lr) * 152 + kk * 32 + lk8];
      halfx8 bf = *(const halfx8*)&kh[(tn * 16 + lr) * 152 + kk * 32 + lk8];
      acc[job] = MFMA16(af, bf, acc[job]);
    }
  }
#pragma unroll
  for (int job = 0; job < 8; ++job) {
    int j2 = w * 8 + job;
    int tm = (j2 & 15) >> 2, tn = j2 & 3;
    int jcol = tn * 16 + lr;
    float cj = sc_c[jcol];
#pragma unroll
    for (int r = 0; r < 4; ++r) {
      int trow = tm * 16 + q4 + r;
      float val = acc[job][r] * __expf(sc_c[trow] - cj);
      if (j2 < 16) {
        LT[jcol * 68 + trow] = (jcol < trow) ? sc_beta[trow] * val : 0.f;
      } else {
        Ph[trow * 88 + jcol] = (_Float16)((jcol <= trow) ? val : 0.f);
      }
    }
  }
  __syncthreads();

  // forward substitution (I+L) z = x  (reads all of LT)
#pragma unroll
  for (int t = 0; t < 64; ++t) {
    float zt = z[t];
    const int start = ((t + 1) >> 2) << 2;
#pragma unroll
    for (int t2 = start; t2 < 64; t2 += 4) {
      float4 lv = *(const float4*)&LT[t * 68 + t2];
      z[t2 + 0] -= lv.x * zt;
      z[t2 + 1] -= lv.y * zt;
      z[t2 + 2] -= lv.z * zt;
      z[t2 + 3] -= lv.w * zt;
    }
  }
  // Eacc init (reads qh) — must precede the Wt overwrite of qh
  floatx4 Eacc[8];
#pragma unroll
  for (int ni = 0; ni < 8; ++ni)
#pragma unroll
    for (int r = 0; r < 4; ++r) {
      int trow = w * 16 + q4 + r;
      Eacc[ni][r] = sc_gam[trow] * (float)qh[trow * 152 + ni * 16 + lr];
    }
  __syncthreads();  // A: all LT + qh reads complete

  // Kt = K̂ᵀ (gcr-scaled) into ex-LT region; contiguous-t halfx8 stores
  {
    int d = tid >> 1, tb = (tid & 1) * 32;
#pragma unroll
    for (int j = 0; j < 4; ++j) {
      halfx8 kv;
#pragma unroll
      for (int r = 0; r < 8; ++r) {
        int t = tb + j * 8 + r;
        kv[r] = (_Float16)(sc_gcr[t] * (float)kh[t * 152 + d]);
      }
      *(halfx8*)&Kt[d * 88 + tb + j * 8] = kv;
    }
  }
  // Wt = -Wᵀ into ex-qh region (safe after barrier A)
  if (tid >= 128) {
    int col = tid & 127;
#pragma unroll
    for (int t = 0; t < 64; t += 8) {
      halfx8 wv;
#pragma unroll
      for (int r = 0; r < 8; ++r) wv[r] = (_Float16)(-z[t + r]);
      *(halfx8*)&Wt[col * 88 + t] = wv;
    }
  }
  __syncthreads();  // B: all kh reads (Kt build) complete
  // Dt = Δᵀ into ex-kh region
  if (tid < 128) {
    int col = tid & 127;
#pragma unroll
    for (int t = 0; t < 64; t += 8) {
      halfx8 dv;
#pragma unroll
      for (int r = 0; r < 8; ++r) dv[r] = (_Float16)z[t + r];
      *(halfx8*)&Dt[col * 88 + t] = dv;
    }
  }
  __syncthreads();  // C: Kt/Wt/Dt visible

  // builds: wave w -> M/B row-tiles {w*32, w*32+16}; E/Oloc t-tile w
  floatx4 Macc[2][8], Bacc[2][8], Oacc[8];
  float gC = __expf(sc_c[63]);
#pragma unroll
  for (int mi = 0; mi < 2; ++mi)
#pragma unroll
    for (int ni = 0; ni < 8; ++ni) {
#pragma unroll
      for (int r = 0; r < 4; ++r)
        Macc[mi][ni][r] = ((w * 32 + mi * 16 + q4 + r) == (ni * 16 + lr)) ? gC : 0.f;
      Bacc[mi][ni] = (floatx4){0.f, 0.f, 0.f, 0.f};
    }
#pragma unroll
  for (int ni = 0; ni < 8; ++ni) Oacc[ni] = (floatx4){0.f, 0.f, 0.f, 0.f};
#pragma unroll
  for (int ks = 0; ks < 2; ++ks) {
    halfx8 ka0 = *(const halfx8*)&Kt[(w * 32 + lr) * 88 + ks * 32 + lk8];
    halfx8 ka1 = *(const halfx8*)&Kt[(w * 32 + 16 + lr) * 88 + ks * 32 + lk8];
    halfx8 pa = *(const halfx8*)&Ph[(w * 16 + lr) * 88 + ks * 32 + lk8];
#pragma unroll
    for (int ni = 0; ni < 8; ++ni) {
      halfx8 wb = *(const halfx8*)&Wt[(ni * 16 + lr) * 88 + ks * 32 + lk8];
      halfx8 db = *(const halfx8*)&Dt[(ni * 16 + lr) * 88 + ks * 32 + lk8];
      Macc[0][ni] = MFMA16(ka0, wb, Macc[0][ni]);
      Macc[1][ni] = MFMA16(ka1, wb, Macc[1][ni]);
      Bacc[0][ni] = MFMA16(ka0, db, Bacc[0][ni]);
      Bacc[1][ni] = MFMA16(ka1, db, Bacc[1][ni]);
      Eacc[ni] = MFMA16(pa, wb, Eacc[ni]);
      Oacc[ni] = MFMA16(pa, db, Oacc[ni]);
    }
  }
  // outputs
#pragma unroll
  for (int mi = 0; mi < 2; ++mi)
#pragma unroll
    for (int ni = 0; ni < 8; ++ni)
#pragma unroll
      for (int r = 0; r < 4; ++r) {
        int row = w * 32 + mi * 16 + q4 + r;
        M_out[row * 128 + ni * 16 + lr] = (_Float16)Macc[mi][ni][r];
        B_out[ni * 2048 + row * 16 + lr] = (_Float16)Bacc[mi][ni][r];
      }
#pragma unroll
  for (int ni = 0; ni < 8; ++ni)
#pragma unroll
    for (int r = 0; r < 4; ++r) {
      int trow = w * 16 + q4 + r;
      E_out[trow * 128 + ni * 16 + lr] = (_Float16)Eacc[ni][r];
      ob[(size_t)trow * 128 + ni * 16 + lr] = Oacc[ni][r];
    }
}

// ---------------- phase B: 256 blocks (32 bh x 8 vgroups), serial over 32 chunks ----------------
// Per chunk: S <- M*S + B ; O = E*S + Oloc. M/E prefetched into double-buffered LDS.
// (R7's register-direct variant regressed ~25us — coalesced burst prefetch + LDS
// redistribution wins at 1 wave/SIMD; reverted to the R6 structure.)
// One raw s_barrier per chunk; writer-side lgkmcnt(0) only — NO vmcnt(0) drain, so the
// register-prefetch loads for chunk c+1 stay in flight across the barrier and are waited
// (counted, per-register) only at their ds_write consumers at the end of the chunk.
__global__ __launch_bounds__(256, 1) void phaseB_kernel(const char* __restrict__ pin,
                                                        float* __restrict__ obuf) {
  __shared__ _Float16 Mh[2][128 * 152];
  __shared__ _Float16 Eh[2][64 * 152];
  __shared__ _Float16 St[2][16 * 152];  // S^T double-buffered -> single barrier per chunk

  int bh = blockIdx.x & 31, vg = blockIdx.x >> 5;  // same-bh blocks land on same XCD
  int tid = threadIdx.x, w = tid >> 6, l = tid & 63;
  int lr = l & 15, lk8 = (l >> 4) * 8, q4 = (l >> 4) * 4;
  const char* ub0 = pin + (size_t)(bh * 32) * PA_STRIDE;
  float* ob_base = obuf + (size_t)bh * S_LEN * DVV + vg * 16;

  float4 Mr[8], Er[4];
  float Bc[2][4], Oc[4], Bn[2][4], On[4];

  // chunk 0 operands
  {
    const float4* Mg = (const float4*)ub0;
    const float4* Eg = (const float4*)(ub0 + 32768);
    const _Float16* Bg = (const _Float16*)(ub0 + 49152) + vg * 2048;
#pragma unroll
    for (int j = 0; j < 8; ++j) Mr[j] = Mg[j * 256 + tid];
#pragma unroll
    for (int j = 0; j < 4; ++j) Er[j] = Eg[j * 256 + tid];
#pragma unroll
    for (int mi = 0; mi < 2; ++mi)
#pragma unroll
      for (int r = 0; r < 4; ++r)
        Bc[mi][r] = (float)Bg[(w * 32 + mi * 16 + q4 + r) * 16 + lr];
#pragma unroll
    for (int r = 0; r < 4; ++r)
      Oc[r] = ob_base[(size_t)(w * 16 + q4 + r) * DVV + lr];
#pragma unroll
    for (int j = 0; j < 8; ++j) {
      int n = j * 256 + tid;
      *(float4*)&Mh[0][(n >> 4) * 152 + (n & 15) * 8] = Mr[j];
    }
#pragma unroll
    for (int j = 0; j < 4; ++j) {
      int n = j * 256 + tid;
      *(float4*)&Eh[0][(n >> 4) * 152 + (n & 15) * 8] = Er[j];
    }
    // S_0 = 0
    halfx4 z4;
    z4[0] = (_Float16)0.f; z4[1] = (_Float16)0.f; z4[2] = (_Float16)0.f; z4[3] = (_Float16)0.f;
#pragma unroll
    for (int mi = 0; mi < 2; ++mi)
      *(halfx4*)&St[0][lr * 152 + w * 32 + mi * 16 + q4] = z4;
  }
  asm volatile("s_waitcnt lgkmcnt(0)" ::: "memory");

  for (int c = 0; c < 32; ++c) {
    __builtin_amdgcn_s_barrier();  // makes St[cur]/Mh[cur]/Eh[cur] writes visible; frees nxt buffers
    int cur = c & 1, nxt = cur ^ 1;
    bool have = (c + 1) < 32;
    // prefetch chunk c+1 into registers (independent of serial chain; drains at ds_write below)
    if (have) {
      const char* un = ub0 + (size_t)(c + 1) * PA_STRIDE;
      const float4* Mg = (const float4*)un;
      const float4* Eg = (const float4*)(un + 32768);
      const _Float16* Bg = (const _Float16*)(un + 49152) + vg * 2048;
#pragma unroll
      for (int j = 0; j < 8; ++j) Mr[j] = Mg[j * 256 + tid];
#pragma unroll
      for (int j = 0; j < 4; ++j) Er[j] = Eg[j * 256 + tid];
#pragma unroll
      for (int mi = 0; mi < 2; ++mi)
#pragma unroll
        for (int r = 0; r < 4; ++r)
          Bn[mi][r] = (float)Bg[(w * 32 + mi * 16 + q4 + r) * 16 + lr];
#pragma unroll
      for (int r = 0; r < 4; ++r)
        On[r] = ob_base[(size_t)((c + 1) * 64 + w * 16 + q4 + r) * DVV + lr];
    }
    // S_new = M*S + B ; O = E*S + Oloc
    floatx4 Sn0 = {Bc[0][0], Bc[0][1], Bc[0][2], Bc[0][3]};
    floatx4 Sn1 = {Bc[1][0], Bc[1][1], Bc[1][2], Bc[1][3]};
    floatx4 Oa = {Oc[0], Oc[1], Oc[2], Oc[3]};
#pragma unroll
    for (int ks = 0; ks < 4; ++ks) {
      halfx8 sf = *(const halfx8*)&St[cur][lr * 152 + ks * 32 + lk8];
      halfx8 ma0 = *(const halfx8*)&Mh[cur][(w * 32 + lr) * 152 + ks * 32 + lk8];
      halfx8 ma1 = *(const halfx8*)&Mh[cur][(w * 32 + 16 + lr) * 152 + ks * 32 + lk8];
      halfx8 ea = *(const halfx8*)&Eh[cur][(w * 16 + lr) * 152 + ks * 32 + lk8];
      Sn0 = MFMA16(ma0, sf, Sn0);
      Sn1 = MFMA16(ma1, sf, Sn1);
      Oa = MFMA16(ea, sf, Oa);
    }
    // store O for this chunk (rows are private to this wave; no in-kernel reader)
    {
      float* obr = ob_base + (size_t)c * 64 * DVV;
#pragma unroll
      for (int r = 0; r < 4; ++r)
        obr[(size_t)(w * 16 + q4 + r) * DVV + lr] = Oa[r];
    }
    // stage next-chunk state S^T into the other St buffer (f16 round-trip identical to
    // keeping an f32 carry: the MFMA consumed f16 either way)
#pragma unroll
    for (int mi = 0; mi < 2; ++mi) {
      halfx4 sv;
      floatx4 Sm = mi ? Sn1 : Sn0;
#pragma unroll
      for (int r = 0; r < 4; ++r) sv[r] = (_Float16)Sm[r];
      *(halfx4*)&St[nxt][lr * 152 + w * 32 + mi * 16 + q4] = sv;
    }
    // write prefetched operands into the other buffer (forces counted vmcnt on Mr/Er only)
    if (have) {
#pragma unroll
      for (int j = 0; j < 8; ++j) {
        int n = j * 256 + tid;
        *(float4*)&Mh[nxt][(n >> 4) * 152 + (n & 15) * 8] = Mr[j];
      }
#pragma unroll
      for (int j = 0; j < 4; ++j) {
        int n = j * 256 + tid;
        *(float4*)&Eh[nxt][(n >> 4) * 152 + (n & 15) * 8] = Er[j];
      }
#pragma unroll
      for (int mi = 0; mi < 2; ++mi)
#pragma unroll
        for (int r = 0; r < 4; ++r) Bc[mi][r] = Bn[mi][r];
#pragma unroll
      for (int r = 0; r < 4; ++r) Oc[r] = On[r];
    }
    asm volatile("s_waitcnt lgkmcnt(0)" ::: "memory");  // LDS writes retired before next barrier
  }
}

// ---------------- per-head RMSNorm * out_norm_w * silu(g) -> og fp16 [M, H*DV] ----------------
__global__ __launch_bounds__(256) void normgate_kernel(const float* __restrict__ o_buf,
                                                       const float* __restrict__ g_buf,
                                                       const float* __restrict__ nw,
                                                       _Float16* __restrict__ og) {
  int gid = blockIdx.x * 4 + (threadIdx.x >> 6);
  int lane = threadIdx.x & 63;
  int m = gid >> 4, h = gid & 15;
  int b = m >> 11, s = m & (S_LEN - 1);
  const float* orow = o_buf + ((size_t)(b * NH + h) * S_LEN + s) * DVV;
  float o0 = orow[lane], o1 = orow[lane + 64];
  float ss = o0 * o0 + o1 * o1;
#pragma unroll
  for (int off = 1; off < 64; off <<= 1) ss += __shfl_xor(ss, off);
  float r = rsqrtf(ss * (1.f / 128.f) + 1e-5f);
  size_t gi = (size_t)m * HID + h * DVV;
  float g0 = g_buf[gi + lane], g1 = g_buf[gi + lane + 64];
  og[gi + lane] = (_Float16)(o0 * r * nw[lane] * (g0 * sigmoidf_(g0)));
  og[gi + lane + 64] = (_Float16)(o1 * r * nw[lane + 64] * (g1 * sigmoidf_(g1)));
}

extern "C" void kernel_launch(void* const* d_in, const int* in_sizes, int n_in,
                              void* d_out, int out_size, void* d_ws, size_t ws_size,
                              hipStream_t stream) {
  const float* X      = (const float*)d_in[0];
  const float* qkv_w  = (const float*)d_in[1];
  const float* g_w    = (const float*)d_in[2];
  const float* b_w    = (const float*)d_in[3];
  const float* gk_w   = (const float*)d_in[4];
  const float* conv_w = (const float*)d_in[5];
  const float* norm_w = (const float*)d_in[6];
  const float* o_w    = (const float*)d_in[7];
  float* out = (float*)d_out;

  char* ws = (char*)d_ws;
  // lifetimes: qkv_buf [gemm_qkv..conv]; g_buf [gemm_g..normgate]; pA [phaseA..phaseB];
  // X16 [cvt..gemm_g]; qw16 [cvt..gemm_qkv]; gw16 [cvt..gemm_g]; og16 [normgate..gemm_out]
  float* qkv_buf   = (float*)(ws);                    // [0, 50331648)
  float* g_buf     = (float*)(ws);                    // [0, 33554432)
  _Float16* ow16   = (_Float16*)(ws + 33554432);      // [33554432, 41943040) written after conv
  float* glog      = (float*)(ws + 41943040);         // written after conv (qkv tail dead)
  float* be        = (float*)(ws + 42205184);
  float* qn        = (float*)(ws + 50331648);         // [50331648, 83886080); obuf reuses
  float* kn        = (float*)(ws + 83886080);         // 8 MiB
  float* vn        = (float*)(ws + 92274688);         // 8 MiB
  _Float16* X16    = (_Float16*)(ws + 100663296);     // 16 MiB, dead before phaseA
  _Float16* qw16   = (_Float16*)(ws + 117440512);     // 12 MiB, dead after gemm_qkv
  _Float16* gw16   = (_Float16*)(ws + 130023424);     // 8 MiB, dead after gemm_g
  char*  pA        = (char*)(ws + 100663296);         // 80 MiB [100663296, 184549376)
  _Float16* og16   = (_Float16*)(ws + 100663296);     // reuse pA after phaseB
  float* o_buf     = qn;

  dim3 blk(256);
  cvt_f16<<<dim3(4096), blk, 0, stream>>>(X, X16, 1048576);
  cvt_f16<<<dim3(3072), blk, 0, stream>>>(qkv_w, qw16, 786432);
  cvt_f16<<<dim3(2048), blk, 0, stream>>>(g_w, gw16, 524288);
  // 1) qkv projection
  gemm_bt_f16_2ph<<<dim3(QKV_DIM / 128, M_TOK / 128), blk, 0, stream>>>(X16, qw16, qkv_buf, M_TOK, QKV_DIM, HID);
  // 2) conv + silu + l2norm (consumes qkv_buf); 128 token-tiles x 24 channel slots
  conv_kernel<<<dim3(M_TOK / 32, 24), blk, 0, stream>>>(qkv_buf, conv_w, qn, kn, vn);
  // 3) glog/beta + o_w cvt (into freed qkv region)
  gkb_kernel<<<dim3(M_TOK / 16), blk, 0, stream>>>(X, gk_w, b_w, glog, be);
  cvt_f16<<<dim3(2048), blk, 0, stream>>>(o_w, ow16, 524288);
  // 4) g projection (overwrites qkv_buf head; X16/gw16 die here)
  gemm_bt_f16_2ph<<<dim3(HID / 128, M_TOK / 128), blk, 0, stream>>>(X16, gw16, g_buf, M_TOK, HID, HID);
  // 5) chunked gated delta rule
  phaseA_kernel<<<dim3(1024), blk, 0, stream>>>(qn, kn, vn, glog, be, pA, o_buf);
  phaseB_kernel<<<dim3(256), blk, 0, stream>>>(pA, o_buf);
  // 6) RMSNorm + gate -> og fp16 (pA dead)
  normgate_kernel<<<dim3(M_TOK * NH / 4), blk, 0, stream>>>(o_buf, g_buf, norm_w, og16);
  // 7) output projection
  gemm_bt_f16_2ph<<<dim3(HID / 128, M_TOK / 128), blk, 0, stream>>>(og16, ow16, out, M_TOK, HID, HID);
}